// Round 6
// baseline (133.886 us; speedup 1.0000x reference)
//
#include <hip/hip_runtime.h>
#include <hip/hip_fp16.h>

// ============================================================================
// JResCOPAttn  (B=1, L=1024, D=128, fp32)
//
//   a  = x@Wl.T+bl ; tx = x@Wl2.T+bl2
//   tm[l,m,d] = sum_e a[l,e]*a[m,e]*Wlo[d,e] + blo[d]
//   y[l,d]    = x[l,d] + sum_m mask[l,m]*tm[l,m,d]*tx[m,d]  -> LayerNorm_d
//
// Round 6 == round 4 kernel, third submission (rounds 4+5 both died at
// GPU acquisition — never compiled/ran; no information gained).
// Round 4 rationale (from round-3 counters: MfmaUtil 30.7 / VALUBusy 34.8 /
// 420 serial cyc/iter => no cross-iteration overlap, occupancy-starved):
//   (a) Explicit depth-1 software pipeline: double-buffered A-row registers,
//       next row's ds_reads issued before current row's MFMA+fold.
//   (b) LDS 56->33.5 KB: tx as f16 transposed [d][66], mask as 32xu64 ballot
//       bitmask (preloaded to 8 VGPR/lane, bit-test replaces 4 ds_reads/iter).
//       + __launch_bounds__(256,3): 3 blocks/CU = 12 waves (was 8).
//   (c) MFMA C init = blov (saves 16 VALU add/iter); tx pair-loads (__half2).
// ============================================================================

typedef _Float16 f16x8 __attribute__((ext_vector_type(8)));
typedef float    f32x4 __attribute__((ext_vector_type(4)));
typedef unsigned int       u32;
typedef unsigned long long u64;

#define LL   1024
#define DD   128
#define EPSV 1e-5f

// ---------------------------------------------------------------------------
// prep: a_h = (f16)(x@Wl.T + bl) ; tx = x@Wl2.T + bl2 ; wh = (f16)Wlo
// grid (4,64) x 256 : bx in {0,1} -> a cols [bx*64,..) ; {2,3} -> tx cols
// ---------------------------------------------------------------------------
__global__ __launch_bounds__(256) void prep_kernel(
    const float* __restrict__ x,  const float* __restrict__ Wl,
    const float* __restrict__ bl, const float* __restrict__ Wlo,
    const float* __restrict__ Wl2,const float* __restrict__ bl2,
    _Float16* __restrict__ a_h, float* __restrict__ tx_out,
    _Float16* __restrict__ wh)
{
    __shared__ float xs[16*128];
    __shared__ float wsh[64*129];          // stride 129 dwords: conflict-free
    const int t  = threadIdx.x;
    const int bx = blockIdx.x;
    const int by = blockIdx.y;
    const int l0 = by*16;

    #pragma unroll
    for (int i = 0; i < 8; ++i) { int f = i*256 + t; xs[f] = x[l0*DD + f]; }
    const float* Wsrc = ((bx < 2) ? Wl : Wl2) + (bx & 1)*64*DD;
    #pragma unroll
    for (int i = 0; i < 32; ++i) {
        int f = i*256 + t; int r = f >> 7, k = f & 127;
        wsh[r*129 + k] = Wsrc[f];
    }
    __syncthreads();

    const int col  = t & 63;               // output column within 64-chunk
    const int lsub = t >> 6;               // 4-row l group
    const float4* X4 = (const float4*)xs;
    float acc0 = 0.f, acc1 = 0.f, acc2 = 0.f, acc3 = 0.f;
    #pragma unroll
    for (int k4 = 0; k4 < 32; ++k4) {
        const float* wp = wsh + col*129 + k4*4;
        float4 wv = {wp[0], wp[1], wp[2], wp[3]};   // banks col%32: 2-way max
        float4 x0 = X4[(lsub*4+0)*32 + k4];         // broadcast within wave
        float4 x1 = X4[(lsub*4+1)*32 + k4];
        float4 x2 = X4[(lsub*4+2)*32 + k4];
        float4 x3 = X4[(lsub*4+3)*32 + k4];
        acc0 += wv.x*x0.x + wv.y*x0.y + wv.z*x0.z + wv.w*x0.w;
        acc1 += wv.x*x1.x + wv.y*x1.y + wv.z*x1.z + wv.w*x1.w;
        acc2 += wv.x*x2.x + wv.y*x2.y + wv.z*x2.z + wv.w*x2.w;
        acc3 += wv.x*x3.x + wv.y*x3.y + wv.z*x3.z + wv.w*x3.w;
    }
    const int colg = (bx & 1)*64 + col;
    const float bv = ((bx < 2) ? bl : bl2)[colg];
    if (bx < 2) {
        a_h[(l0+lsub*4+0)*DD + colg] = (_Float16)(acc0 + bv);
        a_h[(l0+lsub*4+1)*DD + colg] = (_Float16)(acc1 + bv);
        a_h[(l0+lsub*4+2)*DD + colg] = (_Float16)(acc2 + bv);
        a_h[(l0+lsub*4+3)*DD + colg] = (_Float16)(acc3 + bv);
    } else {
        tx_out[(l0+lsub*4+0)*DD + colg] = acc0 + bv;
        tx_out[(l0+lsub*4+1)*DD + colg] = acc1 + bv;
        tx_out[(l0+lsub*4+2)*DD + colg] = acc2 + bv;
        tx_out[(l0+lsub*4+3)*DD + colg] = acc3 + bv;
    }

    const int gid = (by*4 + bx)*256 + t;   // Wlo -> f16, once
    if (gid < DD*DD) wh[gid] = (_Float16)Wlo[gid];
}

// ---------------------------------------------------------------------------
// heavy: block = (chunk: 64 m's) x (ltile: 32 l's) x all 128 d.
// 4 waves: w>>1 = l-half (16 l's), w&1 = d-half (64 d's = 4 n-frags).
// Depth-1 pipelined m-loop; LDS = ash 16K + txt 16.5K + mbits 256B.
// ---------------------------------------------------------------------------
__global__ __launch_bounds__(256, 3) void heavy_kernel(
    const _Float16* __restrict__ a_h, const float* __restrict__ tx,
    const _Float16* __restrict__ wh,  const int* __restrict__ mask,
    const float* __restrict__ blo,    float* __restrict__ part)
{
    __shared__ __align__(16) _Float16 ash[64*DD];   // 16 KB, a m-rows
    __shared__ __align__(4)  _Float16 txt[DD*66];   // 16.5 KB, tx^T padded
    __shared__ u64 mbits[32];                       // mask bitmask per l-row
    const int t     = threadIdx.x;
    const int lane  = t & 63, w = t >> 6;
    const int chunk = blockIdx.x;          // 0..15
    const int ltile = blockIdx.y;          // 0..31
    const int l0 = ltile*32, m0 = chunk*64;

    {   // ash: 16 KB = 1024 float4
        const float4* s4 = (const float4*)(a_h + m0*DD);
        float4* d4 = (float4*)ash;
        #pragma unroll
        for (int i = 0; i < 4; ++i) d4[i*256 + t] = s4[i*256 + t];
    }
    {   // txt[d][m] = (f16)tx[m0+m][d]; pad 66 -> staging writes 4-way max
        #pragma unroll
        for (int i = 0; i < 8; ++i) {
            int idx = i*256 + t;           // 2048 float4 groups
            int m = idx >> 5, dg = idx & 31;
            float4 v = *(const float4*)(tx + (m0+m)*DD + dg*4);
            txt[(dg*4+0)*66 + m] = (_Float16)v.x;
            txt[(dg*4+1)*66 + m] = (_Float16)v.y;
            txt[(dg*4+2)*66 + m] = (_Float16)v.z;
            txt[(dg*4+3)*66 + m] = (_Float16)v.w;
        }
    }
    {   // mbits: each wave ballots one l-row's 64 m's per iteration
        #pragma unroll
        for (int i = 0; i < 8; ++i) {
            int idx = i*256 + t;
            int row = idx >> 6, mcol = idx & 63;
            u64 b = __ballot(mask[(l0 + row)*LL + m0 + mcol] != 0);
            if ((t & 63) == 0) mbits[row] = b;
        }
    }
    __syncthreads();

    const int grp = lane >> 4, ln = lane & 15;
    const int wl = w >> 1, wd = w & 1;
    const int lbase = l0 + wl*16;          // this wave's 16 l rows
    const int dbase = wd*64;               // this wave's 64 d cols

    // B fragments (constant): B[e,d]=Wlo[d,e]; frag: col=lane&15, k=(lane>>4)*8+j
    f16x8 bh[4][4];
    #pragma unroll
    for (int nf = 0; nf < 4; ++nf)
        #pragma unroll
        for (int k = 0; k < 4; ++k)
            bh[nf][k] = *(const f16x8*)(wh + (dbase + nf*16 + ln)*DD + k*32 + grp*8);

    // this lane's a_l (A-frag row = lane&15 = l)
    f16x8 al[4];
    #pragma unroll
    for (int k = 0; k < 4; ++k)
        al[k] = *(const f16x8*)(a_h + (lbase + ln)*DD + k*32 + grp*8);

    float blov[4];
    #pragma unroll
    for (int nf = 0; nf < 4; ++nf) blov[nf] = blo[dbase + nf*16 + ln];

    const int lrow0 = wl*16 + grp*4;       // local C-frag rows
    u64 wmb[4];
    #pragma unroll
    for (int r = 0; r < 4; ++r) wmb[r] = mbits[lrow0 + r];

    f32x4 y[4] = {{0,0,0,0},{0,0,0,0},{0,0,0,0},{0,0,0,0}};

    // per-m compute: A-build (pk_mul) -> 16 MFMA (C init = blov) -> masked fold
    auto compute = [&](int m, const f16x8* am, const __half2* tp, bool hi) {
        f16x8 ah[4];
        #pragma unroll
        for (int k = 0; k < 4; ++k) ah[k] = al[k] * am[k];
        f32x4 c[4];
        #pragma unroll
        for (int nf = 0; nf < 4; ++nf)
            c[nf] = f32x4{blov[nf], blov[nf], blov[nf], blov[nf]};
        #pragma unroll
        for (int k = 0; k < 4; ++k) {
            c[0] = __builtin_amdgcn_mfma_f32_16x16x32_f16(ah[k], bh[0][k], c[0], 0,0,0);
            c[1] = __builtin_amdgcn_mfma_f32_16x16x32_f16(ah[k], bh[1][k], c[1], 0,0,0);
            c[2] = __builtin_amdgcn_mfma_f32_16x16x32_f16(ah[k], bh[2][k], c[2], 0,0,0);
            c[3] = __builtin_amdgcn_mfma_f32_16x16x32_f16(ah[k], bh[3][k], c[3], 0,0,0);
        }
        float tv[4];
        #pragma unroll
        for (int nf = 0; nf < 4; ++nf) {
            float2 f2 = __half22float2(tp[nf]);
            tv[nf] = hi ? f2.y : f2.x;
        }
        #pragma unroll
        for (int r = 0; r < 4; ++r) {
            const bool on = ((wmb[r] >> m) & 1ull) != 0;
            #pragma unroll
            for (int nf = 0; nf < 4; ++nf) {
                float s = on ? tv[nf] : 0.0f;
                y[nf][r] = fmaf(s, c[nf][r], y[nf][r]);
            }
        }
    };

    // ---- depth-1 pipeline over m (2 m's per step) ----
    f16x8 amA[4], amB[4];
    __half2 tpA[4], tpB[4];
    #pragma unroll
    for (int k = 0; k < 4; ++k)
        amA[k] = *(const f16x8*)(ash + 0*DD + k*32 + grp*8);
    #pragma unroll
    for (int nf = 0; nf < 4; ++nf)
        tpA[nf] = *(const __half2*)(txt + (dbase + nf*16 + ln)*66 + 0);

    for (int ms = 0; ms < 62; ms += 2) {
        #pragma unroll
        for (int k = 0; k < 4; ++k)
            amB[k] = *(const f16x8*)(ash + (ms+1)*DD + k*32 + grp*8);
        #pragma unroll
        for (int nf = 0; nf < 4; ++nf)
            tpB[nf] = *(const __half2*)(txt + (dbase + nf*16 + ln)*66 + ms + 2);
        compute(ms, amA, tpA, false);
        #pragma unroll
        for (int k = 0; k < 4; ++k)
            amA[k] = *(const f16x8*)(ash + (ms+2)*DD + k*32 + grp*8);
        compute(ms+1, amB, tpA, true);
        #pragma unroll
        for (int nf = 0; nf < 4; ++nf) tpA[nf] = tpB[nf];
    }
    {   // epilogue: ms = 62, 63
        #pragma unroll
        for (int k = 0; k < 4; ++k)
            amB[k] = *(const f16x8*)(ash + 63*DD + k*32 + grp*8);
        compute(62, amA, tpA, false);
        compute(63, amB, tpA, true);
    }

    // part[chunk][l][d], fp32
    float* dst = part + (size_t)chunk*(LL*DD);
    const int mrow0 = lbase + grp*4;
    #pragma unroll
    for (int nf = 0; nf < 4; ++nf)
        #pragma unroll
        for (int r = 0; r < 4; ++r)
            dst[(mrow0 + r)*DD + dbase + nf*16 + ln] = y[nf][r];
}

// ---------------------------------------------------------------------------
// finish: y = x + sum_chunks part ; LayerNorm over d. grid 1024 x 128.
// ---------------------------------------------------------------------------
__global__ __launch_bounds__(128) void finish_kernel(
    const float* __restrict__ x, const float* __restrict__ part,
    const float* __restrict__ gamma, const float* __restrict__ beta,
    float* __restrict__ out)
{
    const int l = blockIdx.x, t = threadIdx.x;
    float v = x[l*DD + t];
    #pragma unroll
    for (int ch = 0; ch < 16; ++ch)
        v += part[((size_t)ch*LL + l)*DD + t];

    float s = v, s2 = v*v;
    #pragma unroll
    for (int o = 32; o > 0; o >>= 1) {     // wave64 butterfly
        s  += __shfl_xor(s, o);
        s2 += __shfl_xor(s2, o);
    }
    __shared__ float red[4];
    if ((t & 63) == 0) { red[(t>>6)*2+0] = s; red[(t>>6)*2+1] = s2; }
    __syncthreads();
    const float S  = red[0] + red[2];
    const float S2 = red[1] + red[3];
    const float mu  = S * (1.0f/128.0f);
    const float var = S2 * (1.0f/128.0f) - mu*mu;
    const float inv = rsqrtf(var + EPSV);
    out[l*DD + t] = (v - mu)*inv*gamma[t] + beta[t];
}

// ---------------------------------------------------------------------------
extern "C" void kernel_launch(void* const* d_in, const int* in_sizes, int n_in,
                              void* d_out, int out_size, void* d_ws, size_t ws_size,
                              hipStream_t stream)
{
    (void)in_sizes; (void)n_in; (void)out_size; (void)ws_size;
    const float* x     = (const float*)d_in[0];
    const int*   mask  = (const int*)  d_in[1];
    const float* Wl    = (const float*)d_in[2];
    const float* bl    = (const float*)d_in[3];
    const float* Wlo   = (const float*)d_in[4];
    const float* blo   = (const float*)d_in[5];
    const float* Wl2   = (const float*)d_in[6];
    const float* bl2   = (const float*)d_in[7];
    const float* gamma = (const float*)d_in[8];
    const float* beta  = (const float*)d_in[9];
    float* out = (float*)d_out;

    // ws layout (9 MB): a_h f16 256K | tx f32 512K | wh f16 32K | part 8M @1M
    char* ws = (char*)d_ws;
    _Float16* a_h  = (_Float16*)(ws);
    float*    tx_b = (float*)   (ws + (256u<<10));
    _Float16* wh   = (_Float16*)(ws + (768u<<10));
    float*    part = (float*)   (ws + (1024u<<10));

    prep_kernel  <<<dim3(4,64),  256, 0, stream>>>(x, Wl, bl, Wlo, Wl2, bl2,
                                                   a_h, tx_b, wh);
    heavy_kernel <<<dim3(16,32), 256, 0, stream>>>(a_h, tx_b, wh, mask, blo, part);
    finish_kernel<<<1024, 128, 0, stream>>>(x, part, gamma, beta, out);
}

// Round 8
// 118.173 us; speedup vs baseline: 1.1330x; 1.1330x over previous
//
#include <hip/hip_runtime.h>
#include <hip/hip_fp16.h>

// ============================================================================
// JResCOPAttn  (B=1, L=1024, D=128, fp32)
//
//   a  = x@Wl.T+bl ; tx = x@Wl2.T+bl2
//   tm[l,m,d] = sum_e a[l,e]*a[m,e]*Wlo[d,e] + blo[d]
//   y[l,d]    = x[l,d] + sum_m mask[l,m]*tm[l,m,d]*tx[m,d]  -> LayerNorm_d
//
// Round 8 == round 7 resubmitted (round 7 died on container failure; never ran).
// Round 7 rationale (round-6 counters: FETCH 38.8MB/WRITE 48MB vs 3.5/8
// expected, VGPR 84 < live set ~190 => __launch_bounds__(256,3) forced
// register SPILL in the m-loop; 87MB scratch @1.4TB/s == the 62µs):
//   (a) __launch_bounds__(256,2): cap 256 VGPR, no spill; 2 blocks/CU
//       (same occupancy as round 3, but now WITH the depth-1 pipeline).
//   (b) De-lambda the loop body (macro, literal indices only — rule #20);
//       no register arrays passed by pointer.
//   (c) tx unpacked to f32 at pair-load; static even/odd selection.
// Keeps: depth-1 pipeline, ballot mask bit-test, C-init=blov, LDS 33.5KB.
// ============================================================================

typedef _Float16 f16x8 __attribute__((ext_vector_type(8)));
typedef float    f32x4 __attribute__((ext_vector_type(4)));
typedef unsigned int       u32;
typedef unsigned long long u64;

#define LL   1024
#define DD   128
#define EPSV 1e-5f

// ---------------------------------------------------------------------------
// prep: a_h = (f16)(x@Wl.T + bl) ; tx = x@Wl2.T + bl2 ; wh = (f16)Wlo
// grid (4,64) x 256 : bx in {0,1} -> a cols [bx*64,..) ; {2,3} -> tx cols
// ---------------------------------------------------------------------------
__global__ __launch_bounds__(256) void prep_kernel(
    const float* __restrict__ x,  const float* __restrict__ Wl,
    const float* __restrict__ bl, const float* __restrict__ Wlo,
    const float* __restrict__ Wl2,const float* __restrict__ bl2,
    _Float16* __restrict__ a_h, float* __restrict__ tx_out,
    _Float16* __restrict__ wh)
{
    __shared__ float xs[16*128];
    __shared__ float wsh[64*129];          // stride 129 dwords: conflict-free
    const int t  = threadIdx.x;
    const int bx = blockIdx.x;
    const int by = blockIdx.y;
    const int l0 = by*16;

    #pragma unroll
    for (int i = 0; i < 8; ++i) { int f = i*256 + t; xs[f] = x[l0*DD + f]; }
    const float* Wsrc = ((bx < 2) ? Wl : Wl2) + (bx & 1)*64*DD;
    #pragma unroll
    for (int i = 0; i < 32; ++i) {
        int f = i*256 + t; int r = f >> 7, k = f & 127;
        wsh[r*129 + k] = Wsrc[f];
    }
    __syncthreads();

    const int col  = t & 63;               // output column within 64-chunk
    const int lsub = t >> 6;               // 4-row l group
    const float4* X4 = (const float4*)xs;
    float acc0 = 0.f, acc1 = 0.f, acc2 = 0.f, acc3 = 0.f;
    #pragma unroll
    for (int k4 = 0; k4 < 32; ++k4) {
        const float* wp = wsh + col*129 + k4*4;
        float4 wv = {wp[0], wp[1], wp[2], wp[3]};   // banks col%32: 2-way max
        float4 x0 = X4[(lsub*4+0)*32 + k4];         // broadcast within wave
        float4 x1 = X4[(lsub*4+1)*32 + k4];
        float4 x2 = X4[(lsub*4+2)*32 + k4];
        float4 x3 = X4[(lsub*4+3)*32 + k4];
        acc0 += wv.x*x0.x + wv.y*x0.y + wv.z*x0.z + wv.w*x0.w;
        acc1 += wv.x*x1.x + wv.y*x1.y + wv.z*x1.z + wv.w*x1.w;
        acc2 += wv.x*x2.x + wv.y*x2.y + wv.z*x2.z + wv.w*x2.w;
        acc3 += wv.x*x3.x + wv.y*x3.y + wv.z*x3.z + wv.w*x3.w;
    }
    const int colg = (bx & 1)*64 + col;
    const float bv = ((bx < 2) ? bl : bl2)[colg];
    if (bx < 2) {
        a_h[(l0+lsub*4+0)*DD + colg] = (_Float16)(acc0 + bv);
        a_h[(l0+lsub*4+1)*DD + colg] = (_Float16)(acc1 + bv);
        a_h[(l0+lsub*4+2)*DD + colg] = (_Float16)(acc2 + bv);
        a_h[(l0+lsub*4+3)*DD + colg] = (_Float16)(acc3 + bv);
    } else {
        tx_out[(l0+lsub*4+0)*DD + colg] = acc0 + bv;
        tx_out[(l0+lsub*4+1)*DD + colg] = acc1 + bv;
        tx_out[(l0+lsub*4+2)*DD + colg] = acc2 + bv;
        tx_out[(l0+lsub*4+3)*DD + colg] = acc3 + bv;
    }

    const int gid = (by*4 + bx)*256 + t;   // Wlo -> f16, once
    if (gid < DD*DD) wh[gid] = (_Float16)Wlo[gid];
}

// ---------------------------------------------------------------------------
// one m-iteration: A-build (pk_mul) -> 16 MFMA (C init = blov) -> masked fold.
// Macro, not lambda: every array index is a literal after unroll (rule #20).
// ---------------------------------------------------------------------------
#define COMPUTE(MI, AM, TV)                                                   \
  do {                                                                        \
    f16x8 ah_[4];                                                             \
    _Pragma("unroll")                                                         \
    for (int k_ = 0; k_ < 4; ++k_) ah_[k_] = al[k_] * (AM)[k_];               \
    f32x4 c_[4];                                                              \
    _Pragma("unroll")                                                         \
    for (int nf_ = 0; nf_ < 4; ++nf_)                                         \
      c_[nf_] = f32x4{blov[nf_], blov[nf_], blov[nf_], blov[nf_]};            \
    _Pragma("unroll")                                                         \
    for (int k_ = 0; k_ < 4; ++k_) {                                          \
      c_[0] = __builtin_amdgcn_mfma_f32_16x16x32_f16(ah_[k_], bh[0][k_], c_[0],0,0,0); \
      c_[1] = __builtin_amdgcn_mfma_f32_16x16x32_f16(ah_[k_], bh[1][k_], c_[1],0,0,0); \
      c_[2] = __builtin_amdgcn_mfma_f32_16x16x32_f16(ah_[k_], bh[2][k_], c_[2],0,0,0); \
      c_[3] = __builtin_amdgcn_mfma_f32_16x16x32_f16(ah_[k_], bh[3][k_], c_[3],0,0,0); \
    }                                                                         \
    _Pragma("unroll")                                                         \
    for (int r_ = 0; r_ < 4; ++r_) {                                          \
      const bool on_ = ((wmb[r_] >> (MI)) & 1ull) != 0;                       \
      _Pragma("unroll")                                                       \
      for (int nf_ = 0; nf_ < 4; ++nf_)                                       \
        y[nf_][r_] = fmaf(on_ ? (TV)[nf_] : 0.0f, c_[nf_][r_], y[nf_][r_]);   \
    }                                                                         \
  } while (0)

// ---------------------------------------------------------------------------
// heavy: block = (chunk: 64 m's) x (ltile: 32 l's) x all 128 d.
// 4 waves: w>>1 = l-half (16 l's), w&1 = d-half (64 d's = 4 n-frags).
// Depth-1 pipelined m-loop; LDS = ash 16K + txt 16.5K + mbits 256B.
// ---------------------------------------------------------------------------
__global__ __launch_bounds__(256, 2) void heavy_kernel(
    const _Float16* __restrict__ a_h, const float* __restrict__ tx,
    const _Float16* __restrict__ wh,  const int* __restrict__ mask,
    const float* __restrict__ blo,    float* __restrict__ part)
{
    __shared__ __align__(16) _Float16 ash[64*DD];   // 16 KB, a m-rows
    __shared__ __align__(4)  _Float16 txt[DD*66];   // 16.5 KB, tx^T padded
    __shared__ u64 mbits[32];                       // mask bitmask per l-row
    const int t     = threadIdx.x;
    const int lane  = t & 63, w = t >> 6;
    const int chunk = blockIdx.x;          // 0..15
    const int ltile = blockIdx.y;          // 0..31
    const int l0 = ltile*32, m0 = chunk*64;

    {   // ash: 16 KB = 1024 float4
        const float4* s4 = (const float4*)(a_h + m0*DD);
        float4* d4 = (float4*)ash;
        #pragma unroll
        for (int i = 0; i < 4; ++i) d4[i*256 + t] = s4[i*256 + t];
    }
    {   // txt[d][m] = (f16)tx[m0+m][d]
        #pragma unroll
        for (int i = 0; i < 8; ++i) {
            int idx = i*256 + t;           // 2048 float4 groups
            int m = idx >> 5, dg = idx & 31;
            float4 v = *(const float4*)(tx + (m0+m)*DD + dg*4);
            txt[(dg*4+0)*66 + m] = (_Float16)v.x;
            txt[(dg*4+1)*66 + m] = (_Float16)v.y;
            txt[(dg*4+2)*66 + m] = (_Float16)v.z;
            txt[(dg*4+3)*66 + m] = (_Float16)v.w;
        }
    }
    {   // mbits: each wave ballots one l-row's 64 m's per iteration
        #pragma unroll
        for (int i = 0; i < 8; ++i) {
            int idx = i*256 + t;
            int row = idx >> 6, mcol = idx & 63;
            u64 b = __ballot(mask[(l0 + row)*LL + m0 + mcol] != 0);
            if ((t & 63) == 0) mbits[row] = b;
        }
    }
    __syncthreads();

    const int grp = lane >> 4, ln = lane & 15;
    const int wl = w >> 1, wd = w & 1;
    const int lbase = l0 + wl*16;          // this wave's 16 l rows
    const int dbase = wd*64;               // this wave's 64 d cols

    // B fragments (constant): B[e,d]=Wlo[d,e]; frag: col=lane&15, k=(lane>>4)*8+j
    f16x8 bh[4][4];
    #pragma unroll
    for (int nf = 0; nf < 4; ++nf)
        #pragma unroll
        for (int k = 0; k < 4; ++k)
            bh[nf][k] = *(const f16x8*)(wh + (dbase + nf*16 + ln)*DD + k*32 + grp*8);

    // this lane's a_l (A-frag row = lane&15 = l)
    f16x8 al[4];
    #pragma unroll
    for (int k = 0; k < 4; ++k)
        al[k] = *(const f16x8*)(a_h + (lbase + ln)*DD + k*32 + grp*8);

    float blov[4];
    #pragma unroll
    for (int nf = 0; nf < 4; ++nf) blov[nf] = blo[dbase + nf*16 + ln];

    const int lrow0 = wl*16 + grp*4;       // local C-frag rows
    u64 wmb[4];
    #pragma unroll
    for (int r = 0; r < 4; ++r) wmb[r] = mbits[lrow0 + r];

    f32x4 y[4] = {{0,0,0,0},{0,0,0,0},{0,0,0,0},{0,0,0,0}};

    // ---- depth-1 pipeline over m (2 m's per step) ----
    f16x8 amA[4], amB[4];
    float tvA[4], tvB[4], tvC[4], tvD[4];
    #pragma unroll
    for (int k = 0; k < 4; ++k)
        amA[k] = *(const f16x8*)(ash + 0*DD + k*32 + grp*8);
    #pragma unroll
    for (int nf = 0; nf < 4; ++nf) {
        float2 f2 = __half22float2(*(const __half2*)(txt + (dbase + nf*16 + ln)*66));
        tvA[nf] = f2.x; tvB[nf] = f2.y;
    }

    for (int ms = 0; ms < 62; ms += 2) {
        #pragma unroll
        for (int k = 0; k < 4; ++k)
            amB[k] = *(const f16x8*)(ash + (ms+1)*DD + k*32 + grp*8);
        #pragma unroll
        for (int nf = 0; nf < 4; ++nf) {   // next tx pair (ms+2, ms+3)
            float2 f2 = __half22float2(
                *(const __half2*)(txt + (dbase + nf*16 + ln)*66 + ms + 2));
            tvC[nf] = f2.x; tvD[nf] = f2.y;
        }
        COMPUTE(ms, amA, tvA);
        #pragma unroll
        for (int k = 0; k < 4; ++k)
            amA[k] = *(const f16x8*)(ash + (ms+2)*DD + k*32 + grp*8);
        COMPUTE(ms+1, amB, tvB);
        #pragma unroll
        for (int nf = 0; nf < 4; ++nf) { tvA[nf] = tvC[nf]; tvB[nf] = tvD[nf]; }
    }
    {   // epilogue: ms = 62, 63
        #pragma unroll
        for (int k = 0; k < 4; ++k)
            amB[k] = *(const f16x8*)(ash + 63*DD + k*32 + grp*8);
        COMPUTE(62, amA, tvA);
        COMPUTE(63, amB, tvB);
    }

    // part[chunk][l][d], fp32
    float* dst = part + (size_t)chunk*(LL*DD);
    const int mrow0 = lbase + grp*4;
    #pragma unroll
    for (int nf = 0; nf < 4; ++nf)
        #pragma unroll
        for (int r = 0; r < 4; ++r)
            dst[(mrow0 + r)*DD + dbase + nf*16 + ln] = y[nf][r];
}

// ---------------------------------------------------------------------------
// finish: y = x + sum_chunks part ; LayerNorm over d. grid 1024 x 128.
// ---------------------------------------------------------------------------
__global__ __launch_bounds__(128) void finish_kernel(
    const float* __restrict__ x, const float* __restrict__ part,
    const float* __restrict__ gamma, const float* __restrict__ beta,
    float* __restrict__ out)
{
    const int l = blockIdx.x, t = threadIdx.x;
    float v = x[l*DD + t];
    #pragma unroll
    for (int ch = 0; ch < 16; ++ch)
        v += part[((size_t)ch*LL + l)*DD + t];

    float s = v, s2 = v*v;
    #pragma unroll
    for (int o = 32; o > 0; o >>= 1) {     // wave64 butterfly
        s  += __shfl_xor(s, o);
        s2 += __shfl_xor(s2, o);
    }
    __shared__ float red[4];
    if ((t & 63) == 0) { red[(t>>6)*2+0] = s; red[(t>>6)*2+1] = s2; }
    __syncthreads();
    const float S  = red[0] + red[2];
    const float S2 = red[1] + red[3];
    const float mu  = S * (1.0f/128.0f);
    const float var = S2 * (1.0f/128.0f) - mu*mu;
    const float inv = rsqrtf(var + EPSV);
    out[l*DD + t] = (v - mu)*inv*gamma[t] + beta[t];
}

// ---------------------------------------------------------------------------
extern "C" void kernel_launch(void* const* d_in, const int* in_sizes, int n_in,
                              void* d_out, int out_size, void* d_ws, size_t ws_size,
                              hipStream_t stream)
{
    (void)in_sizes; (void)n_in; (void)out_size; (void)ws_size;
    const float* x     = (const float*)d_in[0];
    const int*   mask  = (const int*)  d_in[1];
    const float* Wl    = (const float*)d_in[2];
    const float* bl    = (const float*)d_in[3];
    const float* Wlo   = (const float*)d_in[4];
    const float* blo   = (const float*)d_in[5];
    const float* Wl2   = (const float*)d_in[6];
    const float* bl2   = (const float*)d_in[7];
    const float* gamma = (const float*)d_in[8];
    const float* beta  = (const float*)d_in[9];
    float* out = (float*)d_out;

    // ws layout (9 MB): a_h f16 256K | tx f32 512K | wh f16 32K | part 8M @1M
    char* ws = (char*)d_ws;
    _Float16* a_h  = (_Float16*)(ws);
    float*    tx_b = (float*)   (ws + (256u<<10));
    _Float16* wh   = (_Float16*)(ws + (768u<<10));
    float*    part = (float*)   (ws + (1024u<<10));

    prep_kernel  <<<dim3(4,64),  256, 0, stream>>>(x, Wl, bl, Wlo, Wl2, bl2,
                                                   a_h, tx_b, wh);
    heavy_kernel <<<dim3(16,32), 256, 0, stream>>>(a_h, tx_b, wh, mask, blo, part);
    finish_kernel<<<1024, 128, 0, stream>>>(x, part, gamma, beta, out);
}

// Round 9
// 117.437 us; speedup vs baseline: 1.1401x; 1.0063x over previous
//
#include <hip/hip_runtime.h>
#include <hip/hip_fp16.h>

// ============================================================================
// JResCOPAttn  (B=1, L=1024, D=128, fp32)
//
//   a  = x@Wl.T+bl ; tx = x@Wl2.T+bl2
//   tm[l,m,d] = sum_e a[l,e]*a[m,e]*Wlo[d,e] + blo[d]
//   y[l,d]    = x[l,d] + sum_m mask[l,m]*tm[l,m,d]*tx[m,d]  -> LayerNorm_d
//
// Round 9 (round-8 counters: 830 cyc/wave-iter; MFMA needs 310 (Util 32%),
// VALU 356 (43%), stall ~25%; occupancy GRID-CAPPED at 2 blocks/CU):
//   (a) m-split: chunk 64->32 m's, grid 32x32=1024 blocks = 4 blocks/CU.
//       LDS 33.5->16.8 KB; total staging bytes unchanged. TLP fills stall.
//   (b) part -> f16 (32 chunks x 256KB = 8.4MB, same ws bytes as before).
//   (c) VALU diet: mask bitmask u64->u32 (1-instr shift), tv prefetch
//       registers/copies dropped (fold consumes tv ~200cyc after issue;
//       counted lgkmcnt hides the b32 read).
// Keeps: depth-1 A-row pipeline, ballot mask, C-init=blov, macro body.
// ============================================================================

typedef _Float16 f16x8 __attribute__((ext_vector_type(8)));
typedef float    f32x4 __attribute__((ext_vector_type(4)));
typedef unsigned int       u32;
typedef unsigned long long u64;

#define LL   1024
#define DD   128
#define MCH  32            // m's per chunk
#define TPAD 34            // txt row pad (f16 elems)
#define EPSV 1e-5f

// ---------------------------------------------------------------------------
// prep: a_h = (f16)(x@Wl.T + bl) ; tx = x@Wl2.T + bl2 ; wh = (f16)Wlo
// grid (4,64) x 256 : bx in {0,1} -> a cols [bx*64,..) ; {2,3} -> tx cols
// ---------------------------------------------------------------------------
__global__ __launch_bounds__(256) void prep_kernel(
    const float* __restrict__ x,  const float* __restrict__ Wl,
    const float* __restrict__ bl, const float* __restrict__ Wlo,
    const float* __restrict__ Wl2,const float* __restrict__ bl2,
    _Float16* __restrict__ a_h, float* __restrict__ tx_out,
    _Float16* __restrict__ wh)
{
    __shared__ float xs[16*128];
    __shared__ float wsh[64*129];          // stride 129 dwords: conflict-free
    const int t  = threadIdx.x;
    const int bx = blockIdx.x;
    const int by = blockIdx.y;
    const int l0 = by*16;

    #pragma unroll
    for (int i = 0; i < 8; ++i) { int f = i*256 + t; xs[f] = x[l0*DD + f]; }
    const float* Wsrc = ((bx < 2) ? Wl : Wl2) + (bx & 1)*64*DD;
    #pragma unroll
    for (int i = 0; i < 32; ++i) {
        int f = i*256 + t; int r = f >> 7, k = f & 127;
        wsh[r*129 + k] = Wsrc[f];
    }
    __syncthreads();

    const int col  = t & 63;               // output column within 64-chunk
    const int lsub = t >> 6;               // 4-row l group
    const float4* X4 = (const float4*)xs;
    float acc0 = 0.f, acc1 = 0.f, acc2 = 0.f, acc3 = 0.f;
    #pragma unroll
    for (int k4 = 0; k4 < 32; ++k4) {
        const float* wp = wsh + col*129 + k4*4;
        float4 wv = {wp[0], wp[1], wp[2], wp[3]};   // banks col%32: 2-way max
        float4 x0 = X4[(lsub*4+0)*32 + k4];         // broadcast within wave
        float4 x1 = X4[(lsub*4+1)*32 + k4];
        float4 x2 = X4[(lsub*4+2)*32 + k4];
        float4 x3 = X4[(lsub*4+3)*32 + k4];
        acc0 += wv.x*x0.x + wv.y*x0.y + wv.z*x0.z + wv.w*x0.w;
        acc1 += wv.x*x1.x + wv.y*x1.y + wv.z*x1.z + wv.w*x1.w;
        acc2 += wv.x*x2.x + wv.y*x2.y + wv.z*x2.z + wv.w*x2.w;
        acc3 += wv.x*x3.x + wv.y*x3.y + wv.z*x3.z + wv.w*x3.w;
    }
    const int colg = (bx & 1)*64 + col;
    const float bv = ((bx < 2) ? bl : bl2)[colg];
    if (bx < 2) {
        a_h[(l0+lsub*4+0)*DD + colg] = (_Float16)(acc0 + bv);
        a_h[(l0+lsub*4+1)*DD + colg] = (_Float16)(acc1 + bv);
        a_h[(l0+lsub*4+2)*DD + colg] = (_Float16)(acc2 + bv);
        a_h[(l0+lsub*4+3)*DD + colg] = (_Float16)(acc3 + bv);
    } else {
        tx_out[(l0+lsub*4+0)*DD + colg] = acc0 + bv;
        tx_out[(l0+lsub*4+1)*DD + colg] = acc1 + bv;
        tx_out[(l0+lsub*4+2)*DD + colg] = acc2 + bv;
        tx_out[(l0+lsub*4+3)*DD + colg] = acc3 + bv;
    }

    const int gid = (by*4 + bx)*256 + t;   // Wlo -> f16, once
    if (gid < DD*DD) wh[gid] = (_Float16)Wlo[gid];
}

// ---------------------------------------------------------------------------
// one m-iteration: A-build (pk_mul) -> 16 MFMA (C init = blov) -> masked fold.
// Macro, not lambda: every array index is a literal after unroll (rule #20).
// ---------------------------------------------------------------------------
#define COMPUTE(MI, AM, TV)                                                   \
  do {                                                                        \
    f16x8 ah_[4];                                                             \
    _Pragma("unroll")                                                         \
    for (int k_ = 0; k_ < 4; ++k_) ah_[k_] = al[k_] * (AM)[k_];               \
    f32x4 c_[4];                                                              \
    _Pragma("unroll")                                                         \
    for (int nf_ = 0; nf_ < 4; ++nf_)                                         \
      c_[nf_] = f32x4{blov[nf_], blov[nf_], blov[nf_], blov[nf_]};            \
    _Pragma("unroll")                                                         \
    for (int k_ = 0; k_ < 4; ++k_) {                                          \
      c_[0] = __builtin_amdgcn_mfma_f32_16x16x32_f16(ah_[k_], bh[0][k_], c_[0],0,0,0); \
      c_[1] = __builtin_amdgcn_mfma_f32_16x16x32_f16(ah_[k_], bh[1][k_], c_[1],0,0,0); \
      c_[2] = __builtin_amdgcn_mfma_f32_16x16x32_f16(ah_[k_], bh[2][k_], c_[2],0,0,0); \
      c_[3] = __builtin_amdgcn_mfma_f32_16x16x32_f16(ah_[k_], bh[3][k_], c_[3],0,0,0); \
    }                                                                         \
    _Pragma("unroll")                                                         \
    for (int r_ = 0; r_ < 4; ++r_) {                                          \
      const bool on_ = ((wmb[r_] >> (MI)) & 1u) != 0;                         \
      _Pragma("unroll")                                                       \
      for (int nf_ = 0; nf_ < 4; ++nf_)                                       \
        y[nf_][r_] = fmaf(on_ ? (TV)[nf_] : 0.0f, c_[nf_][r_], y[nf_][r_]);   \
    }                                                                         \
  } while (0)

// ---------------------------------------------------------------------------
// heavy: block = (chunk: 32 m's) x (ltile: 32 l's) x all 128 d.
// 4 waves: w>>1 = l-half (16 l's), w&1 = d-half (64 d's = 4 n-frags).
// Depth-1 pipelined m-loop; LDS = ash 8K + txt 8.5K + mbits 128B.
// grid 32x32 = 1024 blocks -> 4 blocks/CU (was grid-capped at 2).
// ---------------------------------------------------------------------------
__global__ __launch_bounds__(256, 2) void heavy_kernel(
    const _Float16* __restrict__ a_h, const float* __restrict__ tx,
    const _Float16* __restrict__ wh,  const int* __restrict__ mask,
    const float* __restrict__ blo,    _Float16* __restrict__ part)
{
    __shared__ __align__(16) _Float16 ash[MCH*DD];   // 8 KB, a m-rows
    __shared__ __align__(4)  _Float16 txt[DD*TPAD];  // 8.5 KB, tx^T padded
    __shared__ u32 mbits[32];                        // mask bits per l-row
    const int t     = threadIdx.x;
    const int lane  = t & 63, w = t >> 6;
    const int chunk = blockIdx.x;          // 0..31
    const int ltile = blockIdx.y;          // 0..31
    const int l0 = ltile*32, m0 = chunk*MCH;

    {   // ash: 8 KB = 512 float4, 2/thread
        const float4* s4 = (const float4*)(a_h + m0*DD);
        float4* d4 = (float4*)ash;
        #pragma unroll
        for (int i = 0; i < 2; ++i) d4[i*256 + t] = s4[i*256 + t];
    }
    {   // txt[d][m] = (f16)tx[m0+m][d]
        #pragma unroll
        for (int i = 0; i < 4; ++i) {
            int idx = i*256 + t;           // 1024 float4 groups
            int m = idx >> 5, dg = idx & 31;
            float4 v = *(const float4*)(tx + (m0+m)*DD + dg*4);
            txt[(dg*4+0)*TPAD + m] = (_Float16)v.x;
            txt[(dg*4+1)*TPAD + m] = (_Float16)v.y;
            txt[(dg*4+2)*TPAD + m] = (_Float16)v.z;
            txt[(dg*4+3)*TPAD + m] = (_Float16)v.w;
        }
    }
    {   // mbits: wave covers 2 l-rows x 32 m per ballot
        #pragma unroll
        for (int i = 0; i < 4; ++i) {
            int idx = i*256 + t;
            int row = idx >> 5, mcol = idx & 31;
            u64 b = __ballot(mask[(l0 + row)*LL + m0 + mcol] != 0);
            if (lane == 0)  mbits[row]     = (u32)b;
            if (lane == 32) mbits[row]     = (u32)(b >> 32);  // row is lane's own
        }
    }
    __syncthreads();

    const int grp = lane >> 4, ln = lane & 15;
    const int wl = w >> 1, wd = w & 1;
    const int lbase = l0 + wl*16;          // this wave's 16 l rows
    const int dbase = wd*64;               // this wave's 64 d cols

    // B fragments (constant): B[e,d]=Wlo[d,e]; frag: col=lane&15, k=(lane>>4)*8+j
    f16x8 bh[4][4];
    #pragma unroll
    for (int nf = 0; nf < 4; ++nf)
        #pragma unroll
        for (int k = 0; k < 4; ++k)
            bh[nf][k] = *(const f16x8*)(wh + (dbase + nf*16 + ln)*DD + k*32 + grp*8);

    // this lane's a_l (A-frag row = lane&15 = l)
    f16x8 al[4];
    #pragma unroll
    for (int k = 0; k < 4; ++k)
        al[k] = *(const f16x8*)(a_h + (lbase + ln)*DD + k*32 + grp*8);

    float blov[4];
    #pragma unroll
    for (int nf = 0; nf < 4; ++nf) blov[nf] = blo[dbase + nf*16 + ln];

    const int lrow0 = wl*16 + grp*4;       // local C-frag rows
    u32 wmb[4];
    #pragma unroll
    for (int r = 0; r < 4; ++r) wmb[r] = mbits[lrow0 + r];

    f32x4 y[4] = {{0,0,0,0},{0,0,0,0},{0,0,0,0},{0,0,0,0}};

    // ---- depth-1 pipeline over m (2 m's per step, 32 m total) ----
    f16x8 amA[4], amB[4];
    float tvA[4], tvB[4];
    #pragma unroll
    for (int k = 0; k < 4; ++k)
        amA[k] = *(const f16x8*)(ash + 0*DD + k*32 + grp*8);

    for (int ms = 0; ms < 30; ms += 2) {
        #pragma unroll
        for (int k = 0; k < 4; ++k)
            amB[k] = *(const f16x8*)(ash + (ms+1)*DD + k*32 + grp*8);
        #pragma unroll
        for (int nf = 0; nf < 4; ++nf) {   // tx pair (ms, ms+1): consumed in fold
            float2 f2 = __half22float2(
                *(const __half2*)(txt + (dbase + nf*16 + ln)*TPAD + ms));
            tvA[nf] = f2.x; tvB[nf] = f2.y;
        }
        COMPUTE(ms, amA, tvA);
        #pragma unroll
        for (int k = 0; k < 4; ++k)
            amA[k] = *(const f16x8*)(ash + (ms+2)*DD + k*32 + grp*8);
        COMPUTE(ms+1, amB, tvB);
    }
    {   // epilogue: ms = 30, 31
        #pragma unroll
        for (int k = 0; k < 4; ++k)
            amB[k] = *(const f16x8*)(ash + 31*DD + k*32 + grp*8);
        #pragma unroll
        for (int nf = 0; nf < 4; ++nf) {
            float2 f2 = __half22float2(
                *(const __half2*)(txt + (dbase + nf*16 + ln)*TPAD + 30));
            tvA[nf] = f2.x; tvB[nf] = f2.y;
        }
        COMPUTE(30, amA, tvA);
        COMPUTE(31, amB, tvB);
    }

    // part[chunk][l][d], f16
    _Float16* dst = part + (size_t)chunk*(LL*DD);
    const int mrow0 = lbase + grp*4;
    #pragma unroll
    for (int nf = 0; nf < 4; ++nf)
        #pragma unroll
        for (int r = 0; r < 4; ++r)
            dst[(mrow0 + r)*DD + dbase + nf*16 + ln] = (_Float16)y[nf][r];
}

// ---------------------------------------------------------------------------
// finish: y = x + sum_chunks part ; LayerNorm over d. grid 1024 x 128.
// ---------------------------------------------------------------------------
__global__ __launch_bounds__(128) void finish_kernel(
    const float* __restrict__ x, const _Float16* __restrict__ part,
    const float* __restrict__ gamma, const float* __restrict__ beta,
    float* __restrict__ out)
{
    const int l = blockIdx.x, t = threadIdx.x;
    float v = x[l*DD + t];
    #pragma unroll
    for (int ch = 0; ch < 32; ++ch)
        v += (float)part[((size_t)ch*LL + l)*DD + t];

    float s = v, s2 = v*v;
    #pragma unroll
    for (int o = 32; o > 0; o >>= 1) {     // wave64 butterfly
        s  += __shfl_xor(s, o);
        s2 += __shfl_xor(s2, o);
    }
    __shared__ float red[4];
    if ((t & 63) == 0) { red[(t>>6)*2+0] = s; red[(t>>6)*2+1] = s2; }
    __syncthreads();
    const float S  = red[0] + red[2];
    const float S2 = red[1] + red[3];
    const float mu  = S * (1.0f/128.0f);
    const float var = S2 * (1.0f/128.0f) - mu*mu;
    const float inv = rsqrtf(var + EPSV);
    out[l*DD + t] = (v - mu)*inv*gamma[t] + beta[t];
}

// ---------------------------------------------------------------------------
extern "C" void kernel_launch(void* const* d_in, const int* in_sizes, int n_in,
                              void* d_out, int out_size, void* d_ws, size_t ws_size,
                              hipStream_t stream)
{
    (void)in_sizes; (void)n_in; (void)out_size; (void)ws_size;
    const float* x     = (const float*)d_in[0];
    const int*   mask  = (const int*)  d_in[1];
    const float* Wl    = (const float*)d_in[2];
    const float* bl    = (const float*)d_in[3];
    const float* Wlo   = (const float*)d_in[4];
    const float* blo   = (const float*)d_in[5];
    const float* Wl2   = (const float*)d_in[6];
    const float* bl2   = (const float*)d_in[7];
    const float* gamma = (const float*)d_in[8];
    const float* beta  = (const float*)d_in[9];
    float* out = (float*)d_out;

    // ws layout (~9.4MB): a_h f16 256K | tx f32 512K | wh f16 32K | part f16 8.4M @1M
    char* ws = (char*)d_ws;
    _Float16* a_h  = (_Float16*)(ws);
    float*    tx_b = (float*)   (ws + (256u<<10));
    _Float16* wh   = (_Float16*)(ws + (768u<<10));
    _Float16* part = (_Float16*)(ws + (1024u<<10));

    prep_kernel  <<<dim3(4,64),  256, 0, stream>>>(x, Wl, bl, Wlo, Wl2, bl2,
                                                   a_h, tx_b, wh);
    heavy_kernel <<<dim3(32,32), 256, 0, stream>>>(a_h, tx_b, wh, mask, blo, part);
    finish_kernel<<<1024, 128, 0, stream>>>(x, part, gamma, beta, out);
}